// Round 11
// baseline (399.711 us; speedup 1.0000x reference)
//
#include <hip/hip_runtime.h>
#include <math.h>

constexpr int NB = 4, NS = 2048, ND = 512, NH = 8, NDK = 64;
constexpr int NM = NB * NS, NHD = NH * NDK;

typedef short short8v __attribute__((ext_vector_type(8)));
typedef float f32x16v __attribute__((ext_vector_type(16)));
typedef unsigned int uint4v __attribute__((ext_vector_type(4)));

__device__ __forceinline__ unsigned short f2bf(float f) {
    unsigned u = __float_as_uint(f);
    return (unsigned short)((u + 0x7fffu + ((u >> 16) & 1u)) >> 16);
}
__device__ __forceinline__ float bf2f(unsigned short h) {
    return __uint_as_float(((unsigned)h) << 16);
}

#define MFMA32(a, b, c) __builtin_amdgcn_mfma_f32_32x32x16_bf16(a, b, c, 0, 0, 0)

// ---------------------------------------------------------------------------
// split_x: X fp32 [8192*512] -> Xh, Xl bf16 planes.
// ---------------------------------------------------------------------------
__global__ __launch_bounds__(256) void split_x(
    const float* __restrict__ X, unsigned short* __restrict__ xh,
    unsigned short* __restrict__ xl)
{
    const size_t base = ((size_t)blockIdx.x * 256 + threadIdx.x) * 16;
#pragma unroll
    for (int j = 0; j < 4; ++j) {
        float4 v = *(const float4*)&X[base + 4 * j];
        ushort4 h, l;
        h.x = f2bf(v.x); h.y = f2bf(v.y); h.z = f2bf(v.z); h.w = f2bf(v.w);
        l.x = f2bf(v.x - bf2f(h.x)); l.y = f2bf(v.y - bf2f(h.y));
        l.z = f2bf(v.z - bf2f(h.z)); l.w = f2bf(v.w - bf2f(h.w));
        *(ushort4*)&xh[base + 4 * j] = h;
        *(ushort4*)&xl[base + 4 * j] = l;
    }
}

// ---------------------------------------------------------------------------
// split_wT: W fp32 [512][512] -> WTh, WTl bf16 [n][k] (transposed).
// ---------------------------------------------------------------------------
__global__ __launch_bounds__(256) void split_wT(
    const float* __restrict__ W0, const float* __restrict__ W1,
    const float* __restrict__ W2, const float* __restrict__ W3,
    unsigned short* __restrict__ wth, unsigned short* __restrict__ wtl)
{
    const int z = blockIdx.z;
    const float* W = (z == 0) ? W0 : (z == 1) ? W1 : (z == 2) ? W2 : W3;
    unsigned short* th = wth + (size_t)z * ND * ND;
    unsigned short* tl = wtl + (size_t)z * ND * ND;

    __shared__ float T[64][68];
    const int t = threadIdx.x;
    const int k0 = blockIdx.y * 64, n0 = blockIdx.x * 64;
    {
        const int r = t >> 2, c4 = (t & 3) * 16;
#pragma unroll
        for (int j = 0; j < 4; ++j)
            *(float4*)&T[r][c4 + 4 * j] = *(const float4*)&W[(size_t)(k0 + r) * ND + n0 + c4 + 4 * j];
    }
    __syncthreads();
    {
        const int r = t >> 2, c4 = (t & 3) * 16;
        unsigned short* dh = th + (size_t)(n0 + r) * ND + k0 + c4;
        unsigned short* dl = tl + (size_t)(n0 + r) * ND + k0 + c4;
#pragma unroll
        for (int j = 0; j < 4; ++j) {
            ushort4 h, l;
#pragma unroll
            for (int e = 0; e < 4; ++e) {
                float v = T[c4 + 4 * j + e][r];
                unsigned short hh = f2bf(v);
                ((unsigned short*)&h)[e] = hh;
                ((unsigned short*)&l)[e] = f2bf(v - bf2f(hh));
            }
            *(ushort4*)(dh + 4 * j) = h;
            *(ushort4*)(dl + 4 * j) = l;
        }
    }
}

// ---------------------------------------------------------------------------
// proj_qkv_mfma: C = X @ W + b via 3-term split-bf16 MFMA. 128x128 tile,
// BK=64, 4 waves (2x2). z: 0=q (pre-scaled by 0.125*log2e), 1=k, 2=v (hi only).
// ---------------------------------------------------------------------------
__global__ __launch_bounds__(256, 2) void proj_qkv_mfma(
    const unsigned short* __restrict__ xh, const unsigned short* __restrict__ xl,
    const unsigned short* __restrict__ wth, const unsigned short* __restrict__ wtl,
    const float* __restrict__ bq, const float* __restrict__ bk,
    const float* __restrict__ bv,
    unsigned short* __restrict__ qh, unsigned short* __restrict__ ql,
    unsigned short* __restrict__ kh, unsigned short* __restrict__ kl,
    unsigned short* __restrict__ vh)
{
    constexpr int AH = 0, AL = 16384, BH = 32768, BL = 49152;
    __shared__ __align__(16) unsigned char smem[65536];

    const int z = blockIdx.z;
    const float* bias = (z == 0) ? bq : (z == 1) ? bk : bv;
    unsigned short* hp = (z == 0) ? qh : (z == 1) ? kh : vh;
    unsigned short* lp = (z == 0) ? ql : (z == 1) ? kl : (unsigned short*)0;
    const float sc = (z == 0) ? 0.18033688011112042f : 1.0f;  // fold softmax scale into Q
    const unsigned char* bth = (const unsigned char*)(wth + (size_t)z * ND * ND);
    const unsigned char* btl = (const unsigned char*)(wtl + (size_t)z * ND * ND);

    const int tid = threadIdx.x, lane = tid & 63, w = tid >> 6;
    const int wm = w >> 1, wn = w & 1;
    const int c = lane & 31, hi = lane >> 5;
    const int m0 = blockIdx.y * 128, n0 = blockIdx.x * 128;

    const unsigned char* ah_base = (const unsigned char*)xh;
    const unsigned char* al_base = (const unsigned char*)xl;

    int rr[4], gg[4], dd[4];
#pragma unroll
    for (int i = 0; i < 4; ++i) {
        int G = tid + 256 * i;
        rr[i] = G >> 3; gg[i] = G & 7;
        dd[i] = rr[i] * 128 + ((gg[i] ^ (rr[i] & 7)) * 16);
    }

    uint4v sah[4], sal[4], sbh[4], sbl[4];
    auto loads = [&](int kt) {
        const int kb = kt * 128;
#pragma unroll
        for (int i = 0; i < 4; ++i) {
            const size_t arow = (size_t)(m0 + rr[i]) * 1024 + kb + gg[i] * 16;
            const size_t brow = (size_t)(n0 + rr[i]) * 1024 + kb + gg[i] * 16;
            sah[i] = *(const uint4v*)(ah_base + arow);
            sal[i] = *(const uint4v*)(al_base + arow);
            sbh[i] = *(const uint4v*)(bth + brow);
            sbl[i] = *(const uint4v*)(btl + brow);
        }
    };
    auto writes = [&]() {
#pragma unroll
        for (int i = 0; i < 4; ++i) {
            *(uint4v*)(smem + AH + dd[i]) = sah[i];
            *(uint4v*)(smem + AL + dd[i]) = sal[i];
            *(uint4v*)(smem + BH + dd[i]) = sbh[i];
            *(uint4v*)(smem + BL + dd[i]) = sbl[i];
        }
    };

    f32x16v acc[2][2];
#pragma unroll
    for (int a = 0; a < 2; ++a)
#pragma unroll
        for (int bq2 = 0; bq2 < 2; ++bq2)
#pragma unroll
            for (int r = 0; r < 16; ++r) acc[a][bq2][r] = 0.f;

    loads(0);
    for (int kt = 0; kt < ND / 64; ++kt) {
        __syncthreads();
        writes();
        if (kt + 1 < ND / 64) loads(kt + 1);
        __syncthreads();
#pragma unroll
        for (int ks = 0; ks < 4; ++ks) {
            short8v afh[2], afl[2], bfh[2], bfl[2];
#pragma unroll
            for (int ms = 0; ms < 2; ++ms) {
                const int row = wm * 64 + ms * 32 + c;
                const int gb = row * 128 + (((2 * ks + hi) ^ (c & 7)) * 16);
                afh[ms] = *(const short8v*)(smem + AH + gb);
                afl[ms] = *(const short8v*)(smem + AL + gb);
            }
#pragma unroll
            for (int ns = 0; ns < 2; ++ns) {
                const int row = wn * 64 + ns * 32 + c;
                const int gb = row * 128 + (((2 * ks + hi) ^ (c & 7)) * 16);
                bfh[ns] = *(const short8v*)(smem + BH + gb);
                bfl[ns] = *(const short8v*)(smem + BL + gb);
            }
#pragma unroll
            for (int ms = 0; ms < 2; ++ms)
#pragma unroll
                for (int ns = 0; ns < 2; ++ns) {
                    acc[ms][ns] = MFMA32(afh[ms], bfh[ns], acc[ms][ns]);
                    acc[ms][ns] = MFMA32(afh[ms], bfl[ns], acc[ms][ns]);
                    acc[ms][ns] = MFMA32(afl[ms], bfh[ns], acc[ms][ns]);
                }
        }
    }

    const int b = m0 >> 11;
    const int s_base = (m0 & (NS - 1)) + wm * 64;
#pragma unroll
    for (int ns = 0; ns < 2; ++ns) {
        const int n = n0 + wn * 64 + ns * 32 + c;
        const int h = n >> 6, dk = n & (NDK - 1);
        const float bv4 = bias[n];
        const size_t bhBase = (size_t)(b * NH + h) * NS * NDK + dk;
#pragma unroll
        for (int ms = 0; ms < 2; ++ms)
#pragma unroll
            for (int r = 0; r < 16; ++r) {
                const int s = s_base + ms * 32 + (r & 3) + 8 * (r >> 2) + 4 * hi;
                const float v = (acc[ms][ns][r] + bv4) * sc;
                const unsigned short h0 = f2bf(v);
                hp[bhBase + (size_t)s * NDK] = h0;
                if (lp) lp[bhBase + (size_t)s * NDK] = f2bf(v - bf2f(h0));
            }
    }
}

// ---------------------------------------------------------------------------
// vt_convert: V hi plane [bh][s][dv] -> [bh][dv][s].
// ---------------------------------------------------------------------------
__global__ __launch_bounds__(256) void vt_convert(
    const unsigned short* __restrict__ vh, unsigned short* __restrict__ vth)
{
    const int bh = blockIdx.y;
    const int s0 = blockIdx.x * 64;
    __shared__ unsigned short th[64][72];
    const int t = threadIdx.x;
    {
        const int sl = t & 63, ch = (t >> 6) * 16;
        const unsigned short* sh = vh + ((size_t)bh * NS + s0 + sl) * NDK + ch;
#pragma unroll
        for (int j = 0; j < 4; ++j)
            *(ushort4*)&th[sl][ch + 4 * j] = *(const ushort4*)(sh + 4 * j);
    }
    __syncthreads();
    {
        const int dv = t >> 2, sc = (t & 3) * 16;
        unsigned short* dh = vth + ((size_t)bh * NDK + dv) * NS + s0 + sc;
#pragma unroll
        for (int j = 0; j < 4; ++j) {
            ushort4 oh;
            oh.x = th[sc + 4 * j + 0][dv]; oh.y = th[sc + 4 * j + 1][dv];
            oh.z = th[sc + 4 * j + 2][dv]; oh.w = th[sc + 4 * j + 3][dv];
            *(ushort4*)(dh + 4 * j) = oh;
        }
    }
}

// ---------------------------------------------------------------------------
// attn: MFMA attention. SINGLE-buffered K/V LDS (34.8 KB -> 4 blocks/CU,
// 16 waves/CU) with register prefetch of the next tile. Q pre-scaled so
// p = v_exp_f32(s) * mask; P packed via v_cvt_pk_bf16_f32; denominator from
// rounded P. TLP (4 blocks/CU) hides barrier drains and MFMA latency.
// ---------------------------------------------------------------------------
__global__ __launch_bounds__(256, 4) void attn(
    const unsigned short* __restrict__ qhp, const unsigned short* __restrict__ qlp,
    const unsigned short* __restrict__ khp, const unsigned short* __restrict__ klp,
    const unsigned short* __restrict__ vthp,
    const float* __restrict__ maskp,
    unsigned short* __restrict__ cth)
{
    constexpr int NT = NS / 64;
    constexpr int KH = 0, KL = 8192, VH = 16384;
    constexpr int P_OFF = 24576;           // Ph: 4 waves x 2560 B
    __shared__ __align__(16) unsigned char smem[34816];

    const int tid = threadIdx.x, lane = tid & 63, w = tid >> 6;
    const int bid = blockIdx.x;
    const int xcd = bid & 7, r0 = bid >> 3;
    const int qt = r0 & 15, bh = xcd + 8 * (r0 >> 4);
    const int b = bh >> 3;
    const int q0 = qt * 128;
    const int c = lane & 31, hi = lane >> 5;
    const int csw = (c & 7) * 16;

    unsigned* Ph = (unsigned*)(smem + P_OFF + w * 2560);

    const unsigned char* kh_base = (const unsigned char*)khp + (size_t)bh * NS * 128;
    const unsigned char* kl_base = (const unsigned char*)klp + (size_t)bh * NS * 128;
    const unsigned char* vh_base = (const unsigned char*)vthp + (size_t)bh * 64 * 4096;

    const int G1 = tid, G2 = tid + 256;
    const int r1 = G1 >> 3, g1 = G1 & 7, r2 = G2 >> 3, g2 = G2 & 7;
    const int d1 = r1 * 128 + ((g1 ^ (r1 & 7)) * 16);
    const int d2 = r2 * 128 + ((g2 ^ (r2 & 7)) * 16);

    uint4v skh1, skl1, svh1, skh2, skl2, svh2;
    auto loads = [&](int kt) {
        const size_t ko = (size_t)kt * 8192;
        const size_t vo = (size_t)kt * 128;
        skh1 = *(const uint4v*)(kh_base + ko + (size_t)G1 * 16);
        skh2 = *(const uint4v*)(kh_base + ko + (size_t)G2 * 16);
        skl1 = *(const uint4v*)(kl_base + ko + (size_t)G1 * 16);
        skl2 = *(const uint4v*)(kl_base + ko + (size_t)G2 * 16);
        svh1 = *(const uint4v*)(vh_base + vo + (size_t)r1 * 4096 + g1 * 16);
        svh2 = *(const uint4v*)(vh_base + vo + (size_t)r2 * 4096 + g2 * 16);
    };
    auto writes = [&]() {
        *(uint4v*)(smem + KH + d1) = skh1;
        *(uint4v*)(smem + KH + d2) = skh2;
        *(uint4v*)(smem + KL + d1) = skl1;
        *(uint4v*)(smem + KL + d2) = skl2;
        *(uint4v*)(smem + VH + d1) = svh1;
        *(uint4v*)(smem + VH + d2) = svh2;
    };

    short8v qfh[4], qfl[4];
    {
        const unsigned short* qr  = qhp + ((size_t)bh * NS + q0 + 32 * w + c) * NDK + 8 * hi;
        const unsigned short* qrl = qlp + ((size_t)bh * NS + q0 + 32 * w + c) * NDK + 8 * hi;
#pragma unroll
        for (int km = 0; km < 4; ++km) {
            qfh[km] = *(const short8v*)(qr + km * 16);
            qfl[km] = *(const short8v*)(qrl + km * 16);
        }
    }

    f32x16v acc[2];
#pragma unroll
    for (int d = 0; d < 2; ++d)
#pragma unroll
        for (int r = 0; r < 16; ++r) acc[d][r] = 0.f;
    float dsp0 = 0.f, dsp1 = 0.f, dsp2 = 0.f, dsp3 = 0.f;

    auto compute = [&](int kt) {
#pragma unroll
        for (int kb = 0; kb < 2; ++kb) {
            short8v kfh[4], kfl[4];
            const int rowb = (32 * kb + c) * 128;
#pragma unroll
            for (int km = 0; km < 4; ++km) {
                const int gb = ((2 * km + hi) * 16) ^ csw;
                kfh[km] = *(const short8v*)(smem + KH + rowb + gb);
                kfl[km] = *(const short8v*)(smem + KL + rowb + gb);
            }
            // two independent accumulation chains (8 + 4) to hide MFMA latency
            f32x16v s0, s1;
#pragma unroll
            for (int r = 0; r < 16; ++r) { s0[r] = 0.f; s1[r] = 0.f; }
#pragma unroll
            for (int km = 0; km < 4; ++km) {
                s0 = MFMA32(kfh[km], qfh[km], s0);
                s1 = MFMA32(kfh[km], qfl[km], s1);
            }
#pragma unroll
            for (int km = 0; km < 4; ++km)
                s0 = MFMA32(kfl[km], qfh[km], s0);

            float pm[16];
#pragma unroll
            for (int rr2 = 0; rr2 < 4; ++rr2) {
                float4 mv = *(const float4*)&maskp[(size_t)b * NS + kt * 64 + 32 * kb + 8 * rr2 + 4 * hi];
                pm[4 * rr2 + 0] = mv.x; pm[4 * rr2 + 1] = mv.y;
                pm[4 * rr2 + 2] = mv.z; pm[4 * rr2 + 3] = mv.w;
            }
            // p = exp2(s) * mask (Q pre-scaled); pack pairs; denom from rounded P
            unsigned wph[8];
#pragma unroll
            for (int p2 = 0; p2 < 8; ++p2) {
                float x0 = s0[2 * p2] + s1[2 * p2];
                float x1 = s0[2 * p2 + 1] + s1[2 * p2 + 1];
                float e0, e1;
                asm("v_exp_f32 %0, %1" : "=v"(e0) : "v"(x0));
                asm("v_exp_f32 %0, %1" : "=v"(e1) : "v"(x1));
                e0 *= pm[2 * p2];
                e1 *= pm[2 * p2 + 1];
                unsigned wv;
                asm("v_cvt_pk_bf16_f32 %0, %1, %2" : "=v"(wv) : "v"(e0), "v"(e1));
                wph[p2] = wv;
                float dlo = __uint_as_float(wv << 16);
                float dhi = __uint_as_float(wv & 0xffff0000u);
                if ((p2 & 3) == 0) dsp0 += dlo + dhi;
                else if ((p2 & 3) == 1) dsp1 += dlo + dhi;
                else if ((p2 & 3) == 2) dsp2 += dlo + dhi;
                else dsp3 += dlo + dhi;
            }
#pragma unroll
            for (int rr2 = 0; rr2 < 4; ++rr2) {
                uint2 th2; th2.x = wph[2 * rr2]; th2.y = wph[2 * rr2 + 1];
                *(uint2*)&Ph[c * 20 + 4 * rr2 + 2 * hi] = th2;
            }
            asm volatile("s_waitcnt lgkmcnt(0)" ::: "memory");
            __builtin_amdgcn_sched_barrier(0);
#pragma unroll
            for (int pc2 = 0; pc2 < 2; ++pc2) {
                const int pc = 2 * kb + pc2;
                uint4v th4 = *(const uint4v*)&Ph[c * 20 + 8 * pc2 + 4 * hi];
                short8v pfh = __builtin_bit_cast(short8v, th4);
                const int vgb = ((2 * pc + hi) * 16) ^ csw;
#pragma unroll
                for (int d = 0; d < 2; ++d) {
                    const int vrow = (32 * d + c) * 128;
                    short8v vfh = *(const short8v*)(smem + VH + vrow + vgb);
                    acc[d] = MFMA32(vfh, pfh, acc[d]);
                }
            }
        }
    };

    // prologue: tile0 -> LDS, tile1 -> regs
    loads(0);
    writes();
    loads(1);
    __syncthreads();

    for (int kt = 0; kt < NT; ++kt) {
        compute(kt);
        if (kt + 1 < NT) {
            __syncthreads();               // all reads of current tile done
            writes();                      // tile kt+1 regs -> LDS
            if (kt + 2 < NT) loads(kt + 2);// issue next loads (latency hides
            __syncthreads();               //  under compute of kt+1)
        }
    }

    float dsum = (dsp0 + dsp1) + (dsp2 + dsp3);
    dsum += __shfl_xor(dsum, 32);
    const float inv = 1.0f / (dsum + 1e-8f);
    unsigned short* ohr = cth + (size_t)bh * 64 * NS + q0 + 32 * w + c;
#pragma unroll
    for (int d = 0; d < 2; ++d)
#pragma unroll
        for (int r = 0; r < 16; ++r) {
            const int dv = 32 * d + (r & 3) + 8 * (r >> 2) + 4 * hi;
            ohr[(size_t)dv * NS] = f2bf(acc[d][r] * inv);
        }
}

// ---------------------------------------------------------------------------
// ctx_split: bf16 plane [bh][dv][s] -> natural [b*s][h*64+dv].
// ---------------------------------------------------------------------------
__global__ __launch_bounds__(256) void ctx_split(
    const unsigned short* __restrict__ cth, unsigned short* __restrict__ cnh)
{
    const int bh = blockIdx.y;
    const int b = bh >> 3, h = bh & 7;
    const int s0 = blockIdx.x * 64;
    __shared__ unsigned short th[64][72];
    const int t = threadIdx.x;
    {
        const int rd = t >> 2, sc = (t & 3) * 16;
        const unsigned short* sh = cth + ((size_t)bh * NDK + rd) * NS + s0 + sc;
#pragma unroll
        for (int j = 0; j < 4; ++j)
            *(ushort4*)&th[rd][sc + 4 * j] = *(const ushort4*)(sh + 4 * j);
    }
    __syncthreads();
    {
        const int sl = t >> 2, kc = (t & 3) * 16;
        const size_t m = (size_t)b * NS + s0 + sl;
        unsigned short* dh = cnh + m * NHD + h * NDK + kc;
#pragma unroll
        for (int j = 0; j < 4; ++j) {
            ushort4 hh;
#pragma unroll
            for (int e = 0; e < 4; ++e)
                ((unsigned short*)&hh)[e] = th[kc + 4 * j + e][sl];
            *(ushort4*)(dh + 4 * j) = hh;
        }
    }
}

// ---------------------------------------------------------------------------
// proj_out_mfma: out = ctx(bf16) @ Wo + bo — 2-term split MFMA (A hi-only).
// ---------------------------------------------------------------------------
__global__ __launch_bounds__(256, 2) void proj_out_mfma(
    const unsigned short* __restrict__ cnh,
    const unsigned short* __restrict__ wth, const unsigned short* __restrict__ wtl,
    const float* __restrict__ bo, float* __restrict__ out)
{
    constexpr int AH = 0, BH = 16384, BL = 32768;
    __shared__ __align__(16) unsigned char smem[49152];

    const int tid = threadIdx.x, lane = tid & 63, w = tid >> 6;
    const int wm = w >> 1, wn = w & 1;
    const int c = lane & 31, hi = lane >> 5;
    const int m0 = blockIdx.y * 128, n0 = blockIdx.x * 128;

    const unsigned char* ah_base = (const unsigned char*)cnh;
    const unsigned char* bth = (const unsigned char*)wth;
    const unsigned char* btl = (const unsigned char*)wtl;

    int rr[4], gg[4], dd[4];
#pragma unroll
    for (int i = 0; i < 4; ++i) {
        int G = tid + 256 * i;
        rr[i] = G >> 3; gg[i] = G & 7;
        dd[i] = rr[i] * 128 + ((gg[i] ^ (rr[i] & 7)) * 16);
    }

    uint4v sah[4], sbh[4], sbl[4];
    auto loads = [&](int kt) {
        const int kb = kt * 128;
#pragma unroll
        for (int i = 0; i < 4; ++i) {
            const size_t arow = (size_t)(m0 + rr[i]) * 1024 + kb + gg[i] * 16;
            const size_t brow = (size_t)(n0 + rr[i]) * 1024 + kb + gg[i] * 16;
            sah[i] = *(const uint4v*)(ah_base + arow);
            sbh[i] = *(const uint4v*)(bth + brow);
            sbl[i] = *(const uint4v*)(btl + brow);
        }
    };
    auto writes = [&]() {
#pragma unroll
        for (int i = 0; i < 4; ++i) {
            *(uint4v*)(smem + AH + dd[i]) = sah[i];
            *(uint4v*)(smem + BH + dd[i]) = sbh[i];
            *(uint4v*)(smem + BL + dd[i]) = sbl[i];
        }
    };

    f32x16v acc[2][2];
#pragma unroll
    for (int a = 0; a < 2; ++a)
#pragma unroll
        for (int bq2 = 0; bq2 < 2; ++bq2)
#pragma unroll
            for (int r = 0; r < 16; ++r) acc[a][bq2][r] = 0.f;

    loads(0);
    for (int kt = 0; kt < NHD / 64; ++kt) {
        __syncthreads();
        writes();
        if (kt + 1 < NHD / 64) loads(kt + 1);
        __syncthreads();
#pragma unroll
        for (int ks = 0; ks < 4; ++ks) {
            short8v afh[2], bfh[2], bfl[2];
#pragma unroll
            for (int ms = 0; ms < 2; ++ms) {
                const int row = wm * 64 + ms * 32 + c;
                const int gb = row * 128 + (((2 * ks + hi) ^ (c & 7)) * 16);
                afh[ms] = *(const short8v*)(smem + AH + gb);
            }
#pragma unroll
            for (int ns = 0; ns < 2; ++ns) {
                const int row = wn * 64 + ns * 32 + c;
                const int gb = row * 128 + (((2 * ks + hi) ^ (c & 7)) * 16);
                bfh[ns] = *(const short8v*)(smem + BH + gb);
                bfl[ns] = *(const short8v*)(smem + BL + gb);
            }
#pragma unroll
            for (int ms = 0; ms < 2; ++ms)
#pragma unroll
                for (int ns = 0; ns < 2; ++ns) {
                    acc[ms][ns] = MFMA32(afh[ms], bfh[ns], acc[ms][ns]);
                    acc[ms][ns] = MFMA32(afh[ms], bfl[ns], acc[ms][ns]);
                }
        }
    }

#pragma unroll
    for (int ns = 0; ns < 2; ++ns) {
        const int n = n0 + wn * 64 + ns * 32 + c;
        const float bv4 = bo[n];
#pragma unroll
        for (int ms = 0; ms < 2; ++ms)
#pragma unroll
            for (int r = 0; r < 16; ++r) {
                const int m = m0 + wm * 64 + ms * 32 + (r & 3) + 8 * (r >> 2) + 4 * hi;
                out[(size_t)m * ND + n] = acc[ms][ns][r] + bv4;
            }
    }
}

// ---------------------------------------------------------------------------
extern "C" void kernel_launch(void* const* d_in, const int* in_sizes, int n_in,
                              void* d_out, int out_size, void* d_ws, size_t ws_size,
                              hipStream_t stream) {
    const float* Q    = (const float*)d_in[0];
    const float* mask = (const float*)d_in[1];
    const float* Wq   = (const float*)d_in[2];
    const float* bq   = (const float*)d_in[3];
    const float* Wk   = (const float*)d_in[4];
    const float* bk   = (const float*)d_in[5];
    const float* Wv   = (const float*)d_in[6];
    const float* bv   = (const float*)d_in[7];
    const float* Wo   = (const float*)d_in[8];
    const float* bo   = (const float*)d_in[9];

    unsigned char* W = (unsigned char*)d_ws;
    constexpr size_t MB = 1048576;
    // live-range-audited layout (no read/write overlap within any kernel):
    unsigned short* xh   = (unsigned short*)(W + 0);         // split_x .. proj_qkv
    unsigned short* xl   = (unsigned short*)(W + 8 * MB);    // split_x .. proj_qkv
    unsigned short* wtH  = (unsigned short*)(W + 16 * MB);   // split_wT .. proj_out
    unsigned short* wtL  = (unsigned short*)(W + 18 * MB);
    unsigned short* qh   = (unsigned short*)(W + 20 * MB);   // proj_qkv .. attn
    unsigned short* ql   = (unsigned short*)(W + 28 * MB);
    unsigned short* kh   = (unsigned short*)(W + 36 * MB);
    unsigned short* kl   = (unsigned short*)(W + 44 * MB);
    unsigned short* vh   = (unsigned short*)(W + 52 * MB);   // proj_qkv .. vt_convert
    unsigned short* vth  = (unsigned short*)(W + 0);         // vt_convert .. attn (over xh)
    unsigned short* cth  = (unsigned short*)(W + 8 * MB);    // attn .. ctx_split (over xl)
    unsigned short* cnh  = (unsigned short*)(W + 20 * MB);   // ctx_split .. proj_out (over qh)

    split_x<<<NM * ND / (256 * 16), 256, 0, stream>>>(Q, xh, xl);
    split_wT<<<dim3(8, 8, 4), 256, 0, stream>>>(Wq, Wk, Wv, Wo, wtH, wtL);

    proj_qkv_mfma<<<dim3(NHD / 128, NM / 128, 3), 256, 0, stream>>>(
        xh, xl, wtH, wtL, bq, bk, bv, qh, ql, kh, kl, vh);

    vt_convert<<<dim3(NS / 64, NB * NH), 256, 0, stream>>>(vh, vth);

    attn<<<512, 256, 0, stream>>>(qh, ql, kh, kl, vth, mask, cth);

    ctx_split<<<dim3(NS / 64, NB * NH), 256, 0, stream>>>(cth, cnh);

    proj_out_mfma<<<dim3(ND / 128, NM / 128), 256, 0, stream>>>(
        cnh, wtH + (size_t)3 * ND * ND, wtL + (size_t)3 * ND * ND,
        bo, (float*)d_out);
}